// Round 1
// baseline (224.117 us; speedup 1.0000x reference)
//
#include <hip/hip_runtime.h>
#include <math.h>

// Problem constants (B=1, C=256, W=64, N=4096, D=256)
#define N_TOK 4096
#define C_DIM 256
#define D_DIM 256

// workspace layout (float offsets)
#define OFF_GU    0        // 4*256 : g[c]*u[c] per modality
#define OFF_GUBU  1024     // 8 : GU[4], BU[4]
#define OFF_SIM   2048     // 16384
#define OFF_MU    18432    // 16384
#define OFF_RINV  34816    // 16384
#define OFF_ALPHA 51200    // 16384 : attn*rinv
#define OFF_SCAL  67584    // 8 : attnSum[4], P[4]
#define OFF_W     67600    // 4*256 : weighted channel sums
#define OFF_OUTV  68624    // 256
#define OFF_Y     68880    // 256

// ---------------------------------------------------------------------------
// kA: q = t@wt + bt (redundant per block), then per-modality u = wk@q,
//     gu[c] = g[c]*u[c], GU = sum gu, BU = sum be*u.  grid=4, block=256.
__global__ void kA(const float* __restrict__ t, const float* __restrict__ wt,
                   const float* __restrict__ bt,
                   const float* __restrict__ wk0, const float* __restrict__ wk1,
                   const float* __restrict__ wk2, const float* __restrict__ wk3,
                   const float* __restrict__ g0, const float* __restrict__ g1,
                   const float* __restrict__ g2, const float* __restrict__ g3,
                   const float* __restrict__ be0, const float* __restrict__ be1,
                   const float* __restrict__ be2, const float* __restrict__ be3,
                   float* __restrict__ ws) {
  __shared__ float q[256];
  __shared__ float red[4];
  const int tid = threadIdx.x;
  const int m = blockIdx.x;

  float acc = bt[tid];
  #pragma unroll 8
  for (int c = 0; c < 256; ++c) acc += t[c] * wt[c * 256 + tid];
  q[tid] = acc;
  if (m == 0) ws[OFF_OUTV + tid] = 0.0f;   // zero accumulator for kE atomics
  __syncthreads();

  const float* wk = (m == 0) ? wk0 : (m == 1) ? wk1 : (m == 2) ? wk2 : wk3;
  const float* g  = (m == 0) ? g0  : (m == 1) ? g1  : (m == 2) ? g2  : g3;
  const float* be = (m == 0) ? be0 : (m == 1) ? be1 : (m == 2) ? be2 : be3;

  float u = 0.0f;
  const float4* wk4 = (const float4*)(wk + tid * 256);
  #pragma unroll 8
  for (int i = 0; i < 64; ++i) {
    float4 w4 = wk4[i];
    u += w4.x * q[i * 4 + 0] + w4.y * q[i * 4 + 1] +
         w4.z * q[i * 4 + 2] + w4.w * q[i * 4 + 3];
  }
  float guv = g[tid] * u;
  float buv = be[tid] * u;
  ws[OFF_GU + m * 256 + tid] = guv;

  float s = guv;
  for (int o = 32; o > 0; o >>= 1) s += __shfl_down(s, o, 64);
  if ((tid & 63) == 0) red[tid >> 6] = s;
  __syncthreads();
  if (tid == 0) ws[OFF_GUBU + m] = red[0] + red[1] + red[2] + red[3];
  __syncthreads();
  s = buv;
  for (int o = 32; o > 0; o >>= 1) s += __shfl_down(s, o, 64);
  if ((tid & 63) == 0) red[tid >> 6] = s;
  __syncthreads();
  if (tid == 0) ws[OFF_GUBU + 4 + m] = red[0] + red[1] + red[2] + red[3];
}

// ---------------------------------------------------------------------------
// kB: per token j of modality m: single coalesced pass over 256 channels
//     accumulating S1,S2,S3 -> mu, rinv, sim.  grid=256, block=256.
//     Block covers 64 tokens; threads split as (channel-quarter q, token l).
__global__ void kB(const float* __restrict__ A0, const float* __restrict__ A1,
                   const float* __restrict__ A2, const float* __restrict__ A3,
                   float* __restrict__ ws) {
  const int b = blockIdx.x;        // 0..255
  const int m = b >> 6;            // 64 blocks per modality
  const int jbase = (b & 63) * 64;
  const int tid = threadIdx.x;     // 256
  const int l = tid & 63;          // token within tile
  const int qq = tid >> 6;         // channel quarter 0..3
  const float* A = (m == 0) ? A0 : (m == 1) ? A1 : (m == 2) ? A2 : A3;

  __shared__ float gu[256];
  __shared__ float p1[256], p2[256], p3[256];
  gu[tid] = ws[OFF_GU + m * 256 + tid];
  __syncthreads();

  float s1 = 0.f, s2 = 0.f, s3 = 0.f;
  const float* Abase = A + jbase + l;
  #pragma unroll 8
  for (int i = 0; i < 64; ++i) {
    int c = qq * 64 + i;
    float v = Abase[c * N_TOK];
    s1 += v;
    s2 += v * v;
    s3 += v * gu[c];
  }
  p1[tid] = s1; p2[tid] = s2; p3[tid] = s3;
  __syncthreads();
  if (tid < 64) {
    float S1 = p1[tid] + p1[tid + 64] + p1[tid + 128] + p1[tid + 192];
    float S2 = p2[tid] + p2[tid + 64] + p2[tid + 128] + p2[tid + 192];
    float S3 = p3[tid] + p3[tid + 64] + p3[tid + 128] + p3[tid + 192];
    float mu   = S1 * (1.0f / 256.0f);
    float var  = S2 * (1.0f / 256.0f) - mu * mu;
    float rinv = rsqrtf(var + 1e-5f);
    float GU = ws[OFF_GUBU + m];
    float BU = ws[OFF_GUBU + 4 + m];
    float sim = 0.0625f * (rinv * (S3 - mu * GU) + BU);  // scale = 1/sqrt(256)
    int gj = m * N_TOK + jbase + tid;
    ws[OFF_SIM + gj] = sim;
    ws[OFF_MU + gj] = mu;
    ws[OFF_RINV + gj] = rinv;
  }
}

// ---------------------------------------------------------------------------
// kC: softmax over all 16384 sims (one row!), emit alpha = attn*rinv,
//     per-modality scalars attnSum, P = sum attn*rinv*mu.  grid=1, block=1024.
__global__ void kC(float* __restrict__ ws) {
  const int tid = threadIdx.x;  // 0..1023
  __shared__ float red[16];
  float v[4][4];

  float mx = -1e30f;
  #pragma unroll
  for (int m = 0; m < 4; ++m)
    #pragma unroll
    for (int i = 0; i < 4; ++i) {
      float s = ws[OFF_SIM + m * N_TOK + i * 1024 + tid];
      v[m][i] = s;
      mx = fmaxf(mx, s);
    }
  for (int o = 32; o > 0; o >>= 1) mx = fmaxf(mx, __shfl_down(mx, o, 64));
  if ((tid & 63) == 0) red[tid >> 6] = mx;
  __syncthreads();
  mx = red[0];
  #pragma unroll
  for (int w = 1; w < 16; ++w) mx = fmaxf(mx, red[w]);
  __syncthreads();

  float sum = 0.f;
  #pragma unroll
  for (int m = 0; m < 4; ++m)
    #pragma unroll
    for (int i = 0; i < 4; ++i) {
      float e = expf(v[m][i] - mx);
      v[m][i] = e;
      sum += e;
    }
  for (int o = 32; o > 0; o >>= 1) sum += __shfl_down(sum, o, 64);
  if ((tid & 63) == 0) red[tid >> 6] = sum;
  __syncthreads();
  sum = 0.f;
  #pragma unroll
  for (int w = 0; w < 16; ++w) sum += red[w];
  const float inv = 1.0f / sum;

  float accA[4], accP[4];
  #pragma unroll
  for (int m = 0; m < 4; ++m) { accA[m] = 0.f; accP[m] = 0.f; }
  #pragma unroll
  for (int m = 0; m < 4; ++m)
    #pragma unroll
    for (int i = 0; i < 4; ++i) {
      int gj = m * N_TOK + i * 1024 + tid;
      float attn  = v[m][i] * inv;
      float rinv  = ws[OFF_RINV + gj];
      float muv   = ws[OFF_MU + gj];
      float alpha = attn * rinv;
      ws[OFF_ALPHA + gj] = alpha;
      accA[m] += attn;
      accP[m] += alpha * muv;
    }
  #pragma unroll
  for (int m = 0; m < 4; ++m) {
    __syncthreads();
    float s = accA[m];
    for (int o = 32; o > 0; o >>= 1) s += __shfl_down(s, o, 64);
    if ((tid & 63) == 0) red[tid >> 6] = s;
    __syncthreads();
    if (tid == 0) {
      float tt = 0.f;
      for (int w = 0; w < 16; ++w) tt += red[w];
      ws[OFF_SCAL + m] = tt;
    }
    __syncthreads();
    s = accP[m];
    for (int o = 32; o > 0; o >>= 1) s += __shfl_down(s, o, 64);
    if ((tid & 63) == 0) red[tid >> 6] = s;
    __syncthreads();
    if (tid == 0) {
      float tt = 0.f;
      for (int w = 0; w < 16; ++w) tt += red[w];
      ws[OFF_SCAL + 4 + m] = tt;
    }
  }
}

// ---------------------------------------------------------------------------
// kD: wfin_m[c] = g[c]*(sum_j alpha_j*A[c,j] - P_m) + be[c]*attnSum_m.
//     grid=1024 (one block per (m,c)), block=256.
__global__ void kD(const float* __restrict__ A0, const float* __restrict__ A1,
                   const float* __restrict__ A2, const float* __restrict__ A3,
                   const float* __restrict__ g0, const float* __restrict__ g1,
                   const float* __restrict__ g2, const float* __restrict__ g3,
                   const float* __restrict__ be0, const float* __restrict__ be1,
                   const float* __restrict__ be2, const float* __restrict__ be3,
                   float* __restrict__ ws) {
  const int b = blockIdx.x;   // 0..1023
  const int m = b >> 8;
  const int c = b & 255;
  const int tid = threadIdx.x;
  const float* A = (m == 0) ? A0 : (m == 1) ? A1 : (m == 2) ? A2 : A3;
  const float* alpha = ws + OFF_ALPHA + m * N_TOK;
  const float* row = A + c * N_TOK;

  float s = 0.f;
  #pragma unroll 4
  for (int i = 0; i < 16; ++i) {
    int j = i * 256 + tid;
    s += alpha[j] * row[j];
  }
  __shared__ float red[4];
  for (int o = 32; o > 0; o >>= 1) s += __shfl_down(s, o, 64);
  if ((tid & 63) == 0) red[tid >> 6] = s;
  __syncthreads();
  if (tid == 0) {
    float dot = red[0] + red[1] + red[2] + red[3];
    const float* g  = (m == 0) ? g0  : (m == 1) ? g1  : (m == 2) ? g2  : g3;
    const float* be = (m == 0) ? be0 : (m == 1) ? be1 : (m == 2) ? be2 : be3;
    float P  = ws[OFF_SCAL + 4 + m];
    float As = ws[OFF_SCAL + m];
    ws[OFF_W + m * 256 + c] = g[c] * (dot - P) + be[c] * As;
  }
}

// ---------------------------------------------------------------------------
// kE: out_vec[d] += sum_{c chunk} wfin_m[c]*wv_m[c,d].  grid=16, block=256.
__global__ void kE(const float* __restrict__ wv0, const float* __restrict__ wv1,
                   const float* __restrict__ wv2, const float* __restrict__ wv3,
                   float* __restrict__ ws) {
  const int b = blockIdx.x;       // 0..15
  const int m = b >> 2;
  const int cbase = (b & 3) * 64;
  const int d = threadIdx.x;
  const float* wv = (m == 0) ? wv0 : (m == 1) ? wv1 : (m == 2) ? wv2 : wv3;
  float s = 0.f;
  #pragma unroll 8
  for (int i = 0; i < 64; ++i) {
    int c = cbase + i;
    s += ws[OFF_W + m * 256 + c] * wv[c * 256 + d];
  }
  atomicAdd(&ws[OFF_OUTV + d], s);
}

// ---------------------------------------------------------------------------
// kF: tail — layernorm(out_vec), GEGLU, ff2, out projection.  grid=1, block=256.
__global__ void kF(const float* __restrict__ g_res, const float* __restrict__ be_res,
                   const float* __restrict__ w_geglu, const float* __restrict__ b_geglu,
                   const float* __restrict__ w_ff2, const float* __restrict__ b_ff2,
                   const float* __restrict__ w_out, const float* __restrict__ b_out,
                   float* __restrict__ ws) {
  const int tid = threadIdx.x;
  __shared__ float red[4];
  __shared__ float r[256];
  __shared__ float ffin[256];
  __shared__ float ff[256];

  float od = ws[OFF_OUTV + tid];
  float s = od;
  for (int o = 32; o > 0; o >>= 1) s += __shfl_down(s, o, 64);
  if ((tid & 63) == 0) red[tid >> 6] = s;
  __syncthreads();
  float mu = (red[0] + red[1] + red[2] + red[3]) * (1.0f / 256.0f);
  __syncthreads();
  float dv = od - mu;
  s = dv * dv;
  for (int o = 32; o > 0; o >>= 1) s += __shfl_down(s, o, 64);
  if ((tid & 63) == 0) red[tid >> 6] = s;
  __syncthreads();
  float var = (red[0] + red[1] + red[2] + red[3]) * (1.0f / 256.0f);
  float rinv = rsqrtf(var + 1e-5f);
  r[tid] = dv * rinv * g_res[tid] + be_res[tid];
  __syncthreads();

  float ue = b_geglu[tid];
  float ge = b_geglu[256 + tid];
  #pragma unroll 4
  for (int c = 0; c < 256; ++c) {
    float rv = r[c];
    ue += rv * w_geglu[c * 512 + tid];
    ge += rv * w_geglu[c * 512 + 256 + tid];
  }
  float gact = 0.5f * ge * (1.0f + erff(ge * 0.70710678118654752f));
  ffin[tid] = ue * gact;
  __syncthreads();

  float fd = b_ff2[tid];
  #pragma unroll 4
  for (int e = 0; e < 256; ++e) fd += ffin[e] * w_ff2[e * 256 + tid];
  ff[tid] = fd;
  __syncthreads();

  float y = b_out[tid];
  #pragma unroll 4
  for (int d = 0; d < 256; ++d) y += ff[d] * w_out[d * 256 + tid];
  ws[OFF_Y + tid] = y;
}

// ---------------------------------------------------------------------------
// kG: broadcast y[c] over 4096 spatial positions.  grid=1024, block=256, float4.
__global__ void kG(const float* __restrict__ ws, float4* __restrict__ out4) {
  const int idx = blockIdx.x * 256 + threadIdx.x;  // 0..262143
  const int c = idx >> 10;                         // 1024 float4 per channel
  float v = ws[OFF_Y + c];
  out4[idx] = make_float4(v, v, v, v);
}

// ---------------------------------------------------------------------------
extern "C" void kernel_launch(void* const* d_in, const int* in_sizes, int n_in,
                              void* d_out, int out_size, void* d_ws, size_t ws_size,
                              hipStream_t stream) {
  const float* x = (const float*)d_in[0];
  const float* h = (const float*)d_in[1];
  const float* s = (const float*)d_in[2];
  const float* m = (const float*)d_in[3];
  const float* t = (const float*)d_in[4];
  const float* wt = (const float*)d_in[5];
  const float* bt = (const float*)d_in[6];
  const float* wk_x = (const float*)d_in[7];
  const float* wv_x = (const float*)d_in[8];
  const float* g_x = (const float*)d_in[9];
  const float* be_x = (const float*)d_in[10];
  const float* wk_h = (const float*)d_in[11];
  const float* wv_h = (const float*)d_in[12];
  const float* g_h = (const float*)d_in[13];
  const float* be_h = (const float*)d_in[14];
  const float* wk_s = (const float*)d_in[15];
  const float* wv_s = (const float*)d_in[16];
  const float* g_s = (const float*)d_in[17];
  const float* be_s = (const float*)d_in[18];
  const float* wk_m = (const float*)d_in[19];
  const float* wv_m = (const float*)d_in[20];
  const float* g_m = (const float*)d_in[21];
  const float* be_m = (const float*)d_in[22];
  const float* w_geglu = (const float*)d_in[23];
  const float* b_geglu = (const float*)d_in[24];
  const float* w_ff2 = (const float*)d_in[25];
  const float* b_ff2 = (const float*)d_in[26];
  const float* g_res = (const float*)d_in[27];
  const float* be_res = (const float*)d_in[28];
  const float* w_out = (const float*)d_in[29];
  const float* b_out = (const float*)d_in[30];
  float* ws = (float*)d_ws;

  kA<<<dim3(4), dim3(256), 0, stream>>>(t, wt, bt,
      wk_x, wk_h, wk_s, wk_m, g_x, g_h, g_s, g_m, be_x, be_h, be_s, be_m, ws);
  kB<<<dim3(256), dim3(256), 0, stream>>>(x, h, s, m, ws);
  kC<<<dim3(1), dim3(1024), 0, stream>>>(ws);
  kD<<<dim3(1024), dim3(256), 0, stream>>>(x, h, s, m,
      g_x, g_h, g_s, g_m, be_x, be_h, be_s, be_m, ws);
  kE<<<dim3(16), dim3(256), 0, stream>>>(wv_x, wv_h, wv_s, wv_m, ws);
  kF<<<dim3(1), dim3(256), 0, stream>>>(g_res, be_res, w_geglu, b_geglu,
      w_ff2, b_ff2, w_out, b_out, ws);
  kG<<<dim3(1024), dim3(256), 0, stream>>>(ws, (float4*)d_out);
}

// Round 2
// 168.176 us; speedup vs baseline: 1.3326x; 1.3326x over previous
//
#include <hip/hip_runtime.h>
#include <math.h>

// Problem constants (B=1, C=256, W=64, N=4096, D=256)
#define N_TOK 4096

// workspace layout (float offsets)
#define OFF_Q     0        // 256   : q = t@wt + bt (atomic-accumulated, init bt)
#define OFF_GU    256      // 1024  : g[c]*u[c] per modality
#define OFF_GUBU  1280     // 8     : GU[4], BU[4] (atomic, init 0)
#define OFF_SIM   2048     // 16384
#define OFF_MU    18432    // 16384
#define OFF_RINV  34816    // 16384
#define OFF_BLK   51200    // 48    : per softmax block {mx, sumexp, sum exp*rinv*mu}
#define OFF_SOFT  51248    // 10    : M, inv, attnSum[4], P[4] (both pre-multiplied by inv)
#define OFF_W     51264    // 1024  : weighted channel sums per modality
#define OFF_OUTV  52288    // 256   : attention output vector (atomic, init 0)
#define OFF_R     52544    // 256   : layernormed outv
#define OFF_GG    52800    // 512   : geglu pre-activation (atomic, init b_geglu)
#define OFF_FF    53312    // 256   : ff2 output (atomic, init b_ff2)
#define OFF_Y     53568    // 256   : final channel vector (atomic, init b_out)

// ---------------------------------------------------------------------------
// kInit: initialize all atomic accumulators with their biases / zeros.
__global__ void kInit(const float* __restrict__ bt, const float* __restrict__ b_geglu,
                      const float* __restrict__ b_ff2, const float* __restrict__ b_out,
                      float* __restrict__ ws) {
  const int tid = threadIdx.x;  // 512
  ws[OFF_GG + tid] = b_geglu[tid];
  if (tid < 256) {
    ws[OFF_Q + tid] = bt[tid];
    ws[OFF_OUTV + tid] = 0.0f;
    ws[OFF_FF + tid] = b_ff2[tid];
    ws[OFF_Y + tid] = b_out[tid];
  }
  if (tid < 8) ws[OFF_GUBU + tid] = 0.0f;
}

// ---------------------------------------------------------------------------
// kQ: q[d] += sum_{c in chunk} t[c]*wt[c,d].  grid=16, block=256, coalesced.
__global__ void kQ(const float* __restrict__ t, const float* __restrict__ wt,
                   float* __restrict__ ws) {
  const int tid = threadIdx.x;
  const int c0 = blockIdx.x * 16;
  float acc = 0.f;
  #pragma unroll
  for (int i = 0; i < 16; ++i) {
    int c = c0 + i;
    acc += t[c] * wt[c * 256 + tid];
  }
  atomicAdd(&ws[OFF_Q + tid], acc);
}

// ---------------------------------------------------------------------------
// kU: per modality, u[c] = wk[c,:]·q (wave-per-row, coalesced float4),
//     gu[c] = g[c]*u, GU += sum gu, BU += sum be*u.  grid=32, block=256.
__global__ void kU(const float* __restrict__ wk0, const float* __restrict__ wk1,
                   const float* __restrict__ wk2, const float* __restrict__ wk3,
                   const float* __restrict__ g0, const float* __restrict__ g1,
                   const float* __restrict__ g2, const float* __restrict__ g3,
                   const float* __restrict__ be0, const float* __restrict__ be1,
                   const float* __restrict__ be2, const float* __restrict__ be3,
                   float* __restrict__ ws) {
  const int b = blockIdx.x;
  const int m = b >> 3;         // 8 blocks per modality
  const int c0 = (b & 7) * 32;  // 32 rows per block
  const int tid = threadIdx.x;
  const int w = tid >> 6, lane = tid & 63;
  const float* wk = (m == 0) ? wk0 : (m == 1) ? wk1 : (m == 2) ? wk2 : wk3;
  const float* g  = (m == 0) ? g0  : (m == 1) ? g1  : (m == 2) ? g2  : g3;
  const float* be = (m == 0) ? be0 : (m == 1) ? be1 : (m == 2) ? be2 : be3;

  __shared__ float qsh[256];
  __shared__ float red[8];
  qsh[tid] = ws[OFF_Q + tid];
  __syncthreads();
  const float4 qv = ((const float4*)qsh)[lane];

  float lGU = 0.f, lBU = 0.f;
  #pragma unroll
  for (int r = 0; r < 8; ++r) {
    int c = c0 + w * 8 + r;
    float4 w4 = ((const float4*)(wk + c * 256))[lane];
    float s = w4.x * qv.x + w4.y * qv.y + w4.z * qv.z + w4.w * qv.w;
    for (int o = 32; o > 0; o >>= 1) s += __shfl_down(s, o, 64);
    if (lane == 0) {
      float u = s;
      float gu = g[c] * u;
      ws[OFF_GU + m * 256 + c] = gu;
      lGU += gu;
      lBU += be[c] * u;
    }
  }
  if (lane == 0) { red[w] = lGU; red[4 + w] = lBU; }
  __syncthreads();
  if (tid == 0) {
    atomicAdd(&ws[OFF_GUBU + m], red[0] + red[1] + red[2] + red[3]);
    atomicAdd(&ws[OFF_GUBU + 4 + m], red[4] + red[5] + red[6] + red[7]);
  }
}

// ---------------------------------------------------------------------------
// kB: per token j of modality m: single coalesced pass over 256 channels
//     accumulating S1,S2,S3 -> mu, rinv, sim.  grid=256, block=256.
__global__ void kB(const float* __restrict__ A0, const float* __restrict__ A1,
                   const float* __restrict__ A2, const float* __restrict__ A3,
                   float* __restrict__ ws) {
  const int b = blockIdx.x;        // 0..255
  const int m = b >> 6;            // 64 blocks per modality
  const int jbase = (b & 63) * 64;
  const int tid = threadIdx.x;     // 256
  const int l = tid & 63;          // token within tile
  const int qq = tid >> 6;         // channel quarter 0..3
  const float* A = (m == 0) ? A0 : (m == 1) ? A1 : (m == 2) ? A2 : A3;

  __shared__ float gu[256];
  __shared__ float p1[256], p2[256], p3[256];
  gu[tid] = ws[OFF_GU + m * 256 + tid];
  __syncthreads();

  float s1 = 0.f, s2 = 0.f, s3 = 0.f;
  const float* Abase = A + jbase + l;
  #pragma unroll 8
  for (int i = 0; i < 64; ++i) {
    int c = qq * 64 + i;
    float v = Abase[c * N_TOK];
    s1 += v;
    s2 += v * v;
    s3 += v * gu[c];
  }
  p1[tid] = s1; p2[tid] = s2; p3[tid] = s3;
  __syncthreads();
  if (tid < 64) {
    float S1 = p1[tid] + p1[tid + 64] + p1[tid + 128] + p1[tid + 192];
    float S2 = p2[tid] + p2[tid + 64] + p2[tid + 128] + p2[tid + 192];
    float S3 = p3[tid] + p3[tid + 64] + p3[tid + 128] + p3[tid + 192];
    float mu   = S1 * (1.0f / 256.0f);
    float var  = S2 * (1.0f / 256.0f) - mu * mu;
    float rinv = rsqrtf(var + 1e-5f);
    float GU = ws[OFF_GUBU + m];
    float BU = ws[OFF_GUBU + 4 + m];
    float sim = 0.0625f * (rinv * (S3 - mu * GU) + BU);  // scale = 1/sqrt(256)
    int gj = m * N_TOK + jbase + tid;
    ws[OFF_SIM + gj] = sim;
    ws[OFF_MU + gj] = mu;
    ws[OFF_RINV + gj] = rinv;
  }
}

// ---------------------------------------------------------------------------
// kC1: per-block softmax partials over 1024 sims: {local max, sum exp,
//      sum exp*rinv*mu}.  grid=16, block=256.
__global__ void kC1(float* __restrict__ ws) {
  const int b = blockIdx.x;
  const int tid = threadIdx.x;
  const int base = b * 1024;       // global sim index base (contiguous over m)
  __shared__ float sred[4];

  float v[4];
  float mx = -1e30f;
  #pragma unroll
  for (int i = 0; i < 4; ++i) {
    v[i] = ws[OFF_SIM + base + i * 256 + tid];
    mx = fmaxf(mx, v[i]);
  }
  for (int o = 32; o > 0; o >>= 1) mx = fmaxf(mx, __shfl_down(mx, o, 64));
  if ((tid & 63) == 0) sred[tid >> 6] = mx;
  __syncthreads();
  const float mxb = fmaxf(fmaxf(sred[0], sred[1]), fmaxf(sred[2], sred[3]));
  __syncthreads();

  float se = 0.f, srm = 0.f;
  #pragma unroll
  for (int i = 0; i < 4; ++i) {
    int idx = base + i * 256 + tid;
    float e = expf(v[i] - mxb);
    se += e;
    srm += e * ws[OFF_RINV + idx] * ws[OFF_MU + idx];
  }
  for (int o = 32; o > 0; o >>= 1) se += __shfl_down(se, o, 64);
  if ((tid & 63) == 0) sred[tid >> 6] = se;
  __syncthreads();
  float seT = sred[0] + sred[1] + sred[2] + sred[3];
  __syncthreads();
  for (int o = 32; o > 0; o >>= 1) srm += __shfl_down(srm, o, 64);
  if ((tid & 63) == 0) sred[tid >> 6] = srm;
  __syncthreads();
  if (tid == 0) {
    float srmT = sred[0] + sred[1] + sred[2] + sred[3];
    ws[OFF_BLK + b * 3 + 0] = mxb;
    ws[OFF_BLK + b * 3 + 1] = seT;
    ws[OFF_BLK + b * 3 + 2] = srmT;
  }
}

// ---------------------------------------------------------------------------
// kC2: combine 16 partials -> M, inv, per-modality attnSum*inv, P*inv.
__global__ void kC2(float* __restrict__ ws) {
  if (threadIdx.x != 0) return;
  float mx[16], se[16], srm[16];
  float M = -1e30f;
  for (int b = 0; b < 16; ++b) {
    mx[b] = ws[OFF_BLK + b * 3 + 0];
    se[b] = ws[OFF_BLK + b * 3 + 1];
    srm[b] = ws[OFF_BLK + b * 3 + 2];
    M = fmaxf(M, mx[b]);
  }
  float S = 0.f, As[4] = {0, 0, 0, 0}, P[4] = {0, 0, 0, 0};
  for (int b = 0; b < 16; ++b) {
    float f = expf(mx[b] - M);
    int m = b >> 2;
    S += se[b] * f;
    As[m] += se[b] * f;
    P[m] += srm[b] * f;
  }
  float inv = 1.0f / S;
  ws[OFF_SOFT + 0] = M;
  ws[OFF_SOFT + 1] = inv;
  for (int m = 0; m < 4; ++m) {
    ws[OFF_SOFT + 2 + m] = As[m] * inv;
    ws[OFF_SOFT + 6 + m] = P[m] * inv;
  }
}

// ---------------------------------------------------------------------------
// kD: wfin_m[c] = g[c]*(inv*sum_j exp(sim-M)*rinv*A[c,j] - P'_m) + be[c]*As'_m,
//     alpha recomputed inline.  grid=1024 (block per (m,c)), block=256.
__global__ void kD(const float* __restrict__ A0, const float* __restrict__ A1,
                   const float* __restrict__ A2, const float* __restrict__ A3,
                   const float* __restrict__ g0, const float* __restrict__ g1,
                   const float* __restrict__ g2, const float* __restrict__ g3,
                   const float* __restrict__ be0, const float* __restrict__ be1,
                   const float* __restrict__ be2, const float* __restrict__ be3,
                   float* __restrict__ ws) {
  const int b = blockIdx.x;   // 0..1023
  const int m = b >> 8;
  const int c = b & 255;
  const int tid = threadIdx.x;
  const float* A = (m == 0) ? A0 : (m == 1) ? A1 : (m == 2) ? A2 : A3;
  const float* row = A + c * N_TOK;
  const float M = ws[OFF_SOFT + 0];
  const float inv = ws[OFF_SOFT + 1];

  float s = 0.f;
  #pragma unroll 4
  for (int i = 0; i < 16; ++i) {
    int j = i * 256 + tid;
    int gj = m * N_TOK + j;
    float a = expf(ws[OFF_SIM + gj] - M) * ws[OFF_RINV + gj];
    s += a * row[j];
  }
  __shared__ float red[4];
  for (int o = 32; o > 0; o >>= 1) s += __shfl_down(s, o, 64);
  if ((tid & 63) == 0) red[tid >> 6] = s;
  __syncthreads();
  if (tid == 0) {
    float dot = (red[0] + red[1] + red[2] + red[3]) * inv;
    const float* g  = (m == 0) ? g0  : (m == 1) ? g1  : (m == 2) ? g2  : g3;
    const float* be = (m == 0) ? be0 : (m == 1) ? be1 : (m == 2) ? be2 : be3;
    float P  = ws[OFF_SOFT + 6 + m];
    float As = ws[OFF_SOFT + 2 + m];
    ws[OFF_W + m * 256 + c] = g[c] * (dot - P) + be[c] * As;
  }
}

// ---------------------------------------------------------------------------
// kE: outv[d] += sum_{c chunk} wfin_m[c]*wv_m[c,d].  grid=16, block=256.
__global__ void kE(const float* __restrict__ wv0, const float* __restrict__ wv1,
                   const float* __restrict__ wv2, const float* __restrict__ wv3,
                   float* __restrict__ ws) {
  const int b = blockIdx.x;       // 0..15
  const int m = b >> 2;
  const int cbase = (b & 3) * 64;
  const int d = threadIdx.x;
  const float* wv = (m == 0) ? wv0 : (m == 1) ? wv1 : (m == 2) ? wv2 : wv3;
  float s = 0.f;
  #pragma unroll 8
  for (int i = 0; i < 64; ++i) {
    int c = cbase + i;
    s += ws[OFF_W + m * 256 + c] * wv[c * 256 + d];
  }
  atomicAdd(&ws[OFF_OUTV + d], s);
}

// ---------------------------------------------------------------------------
// kT1: r = layernorm(outv)*g_res + be_res.  grid=1, block=256.
__global__ void kT1(const float* __restrict__ g_res, const float* __restrict__ be_res,
                    float* __restrict__ ws) {
  const int tid = threadIdx.x;
  __shared__ float red[4];
  float od = ws[OFF_OUTV + tid];
  float s = od;
  for (int o = 32; o > 0; o >>= 1) s += __shfl_down(s, o, 64);
  if ((tid & 63) == 0) red[tid >> 6] = s;
  __syncthreads();
  float mu = (red[0] + red[1] + red[2] + red[3]) * (1.0f / 256.0f);
  __syncthreads();
  float dv = od - mu;
  s = dv * dv;
  for (int o = 32; o > 0; o >>= 1) s += __shfl_down(s, o, 64);
  if ((tid & 63) == 0) red[tid >> 6] = s;
  __syncthreads();
  float var = (red[0] + red[1] + red[2] + red[3]) * (1.0f / 256.0f);
  ws[OFF_R + tid] = dv * rsqrtf(var + 1e-5f) * g_res[tid] + be_res[tid];
}

// ---------------------------------------------------------------------------
// kT2: gg[dt*256+e] += sum_{d chunk} r[d]*w_geglu[d, dt*256+e].
//      grid=32 (dt 2 x dchunk 16), block=256.
__global__ void kT2(const float* __restrict__ w_geglu, float* __restrict__ ws) {
  const int b = blockIdx.x;
  const int dt = b >> 4;          // output half
  const int d0 = (b & 15) * 16;   // input-row chunk
  const int tid = threadIdx.x;
  float acc = 0.f;
  #pragma unroll
  for (int i = 0; i < 16; ++i) {
    int d = d0 + i;
    acc += ws[OFF_R + d] * w_geglu[d * 512 + dt * 256 + tid];
  }
  atomicAdd(&ws[OFF_GG + dt * 256 + tid], acc);
}

// ---------------------------------------------------------------------------
// kT3: ffin[c] = u*gelu(gate); ff[d] += sum_{c chunk} ffin[c]*w_ff2[c,d].
//      grid=16, block=256.
__global__ void kT3(const float* __restrict__ w_ff2, float* __restrict__ ws) {
  const int c0 = blockIdx.x * 16;
  const int tid = threadIdx.x;
  float acc = 0.f;
  #pragma unroll
  for (int i = 0; i < 16; ++i) {
    int c = c0 + i;
    float u = ws[OFF_GG + c];
    float gate = ws[OFF_GG + 256 + c];
    float f = u * 0.5f * gate * (1.0f + erff(gate * 0.70710678118654752f));
    acc += f * w_ff2[c * 256 + tid];
  }
  atomicAdd(&ws[OFF_FF + tid], acc);
}

// ---------------------------------------------------------------------------
// kT4: y[c] += sum_{d chunk} ff[d]*w_out[d,c].  grid=16, block=256.
__global__ void kT4(const float* __restrict__ w_out, float* __restrict__ ws) {
  const int d0 = blockIdx.x * 16;
  const int tid = threadIdx.x;
  float acc = 0.f;
  #pragma unroll
  for (int i = 0; i < 16; ++i) {
    int d = d0 + i;
    acc += ws[OFF_FF + d] * w_out[d * 256 + tid];
  }
  atomicAdd(&ws[OFF_Y + tid], acc);
}

// ---------------------------------------------------------------------------
// kG: broadcast y[c] over 4096 spatial positions.  grid=1024, block=256, float4.
__global__ void kG(const float* __restrict__ ws, float4* __restrict__ out4) {
  const int idx = blockIdx.x * 256 + threadIdx.x;  // 0..262143
  const int c = idx >> 10;                         // 1024 float4 per channel
  float v = ws[OFF_Y + c];
  out4[idx] = make_float4(v, v, v, v);
}

// ---------------------------------------------------------------------------
extern "C" void kernel_launch(void* const* d_in, const int* in_sizes, int n_in,
                              void* d_out, int out_size, void* d_ws, size_t ws_size,
                              hipStream_t stream) {
  const float* x = (const float*)d_in[0];
  const float* h = (const float*)d_in[1];
  const float* s = (const float*)d_in[2];
  const float* m = (const float*)d_in[3];
  const float* t = (const float*)d_in[4];
  const float* wt = (const float*)d_in[5];
  const float* bt = (const float*)d_in[6];
  const float* wk_x = (const float*)d_in[7];
  const float* wv_x = (const float*)d_in[8];
  const float* g_x = (const float*)d_in[9];
  const float* be_x = (const float*)d_in[10];
  const float* wk_h = (const float*)d_in[11];
  const float* wv_h = (const float*)d_in[12];
  const float* g_h = (const float*)d_in[13];
  const float* be_h = (const float*)d_in[14];
  const float* wk_s = (const float*)d_in[15];
  const float* wv_s = (const float*)d_in[16];
  const float* g_s = (const float*)d_in[17];
  const float* be_s = (const float*)d_in[18];
  const float* wk_m = (const float*)d_in[19];
  const float* wv_m = (const float*)d_in[20];
  const float* g_m = (const float*)d_in[21];
  const float* be_m = (const float*)d_in[22];
  const float* w_geglu = (const float*)d_in[23];
  const float* b_geglu = (const float*)d_in[24];
  const float* w_ff2 = (const float*)d_in[25];
  const float* b_ff2 = (const float*)d_in[26];
  const float* g_res = (const float*)d_in[27];
  const float* be_res = (const float*)d_in[28];
  const float* w_out = (const float*)d_in[29];
  const float* b_out = (const float*)d_in[30];
  float* ws = (float*)d_ws;

  kInit<<<dim3(1), dim3(512), 0, stream>>>(bt, b_geglu, b_ff2, b_out, ws);
  kQ<<<dim3(16), dim3(256), 0, stream>>>(t, wt, ws);
  kU<<<dim3(32), dim3(256), 0, stream>>>(wk_x, wk_h, wk_s, wk_m,
      g_x, g_h, g_s, g_m, be_x, be_h, be_s, be_m, ws);
  kB<<<dim3(256), dim3(256), 0, stream>>>(x, h, s, m, ws);
  kC1<<<dim3(16), dim3(256), 0, stream>>>(ws);
  kC2<<<dim3(1), dim3(64), 0, stream>>>(ws);
  kD<<<dim3(1024), dim3(256), 0, stream>>>(x, h, s, m,
      g_x, g_h, g_s, g_m, be_x, be_h, be_s, be_m, ws);
  kE<<<dim3(16), dim3(256), 0, stream>>>(wv_x, wv_h, wv_s, wv_m, ws);
  kT1<<<dim3(1), dim3(256), 0, stream>>>(g_res, be_res, ws);
  kT2<<<dim3(32), dim3(256), 0, stream>>>(w_geglu, ws);
  kT3<<<dim3(16), dim3(256), 0, stream>>>(w_ff2, ws);
  kT4<<<dim3(16), dim3(256), 0, stream>>>(w_out, ws);
  kG<<<dim3(1024), dim3(256), 0, stream>>>(ws, (float4*)d_out);
}